// Round 2
// baseline (1210.797 us; speedup 1.0000x reference)
//
#include <hip/hip_runtime.h>

// GNN NodeModel on MI355X.
// Edge MLP -> BN(E) -> ReLU -> Linear -> scatter_mean -> Node MLP -> BN(N) -> ReLU -> Linear.
// b1/b3 are skipped: BN mean-subtraction cancels them exactly.

#define HID 64
#define KPAD 104   // A/W tile K stride (96 used; +8 pad -> 208B row stride, 16B aligned, spreads banks)
#define RPAD 72    // relu/W2 tile K stride (64 used; 144B row stride, 16B aligned)
#define BN_EPS 1e-5f

typedef __attribute__((ext_vector_type(8))) short bf16x8;
typedef __attribute__((ext_vector_type(4))) short bf16x4;
typedef __attribute__((ext_vector_type(4))) float f32x4;

static __device__ __forceinline__ short f2bf(float f) {
  union { float fv; unsigned u; } v; v.fv = f;
  unsigned r = v.u + 0x7FFFu + ((v.u >> 16) & 1u);  // round-to-nearest-even
  return (short)(r >> 16);
}

// Stage W^T for the K=96 GEMM: W[k][n] semantics, rows 0..63 = w[3+k][n] (attr part),
// rows 64..66 = w[k-64][n] (x part), rest zero. Stored as Wt[n][k].
static __device__ __forceinline__ void stage_w_k96(short (*W)[KPAD], const float* __restrict__ w, int tid) {
  for (int i = tid; i < 64 * KPAD; i += 256) {
    int n = i / KPAD, k = i - n * KPAD;
    float v = 0.f;
    if (k < 64)      v = w[(size_t)(3 + k) * HID + n];
    else if (k < 67) v = w[(size_t)(k - 64) * HID + n];
    W[n][k] = f2bf(v);
  }
}

static __device__ __forceinline__ void stage_w_k64(short (*W)[RPAD], const float* __restrict__ w, int tid) {
  for (int i = tid; i < 64 * RPAD; i += 256) {
    int n = i / RPAD, k = i - n * RPAD;
    float v = (k < 64) ? w[(size_t)k * HID + n] : 0.f;
    W[n][k] = f2bf(v);
  }
}

// 64x64 tile, K=96, 4 waves each owning 16 rows. A-frag: row=l&15, k=(l>>4)*8+j.
// B-frag from Wt[n][k]: col=l&15, same k split. C/D: col=lane&15, row=(lane>>4)*4+reg.
static __device__ __forceinline__ void gemm_k96(const short (*A)[KPAD], const short (*W)[KPAD],
                                                int wv, int l15, int kg, f32x4* acc) {
  const int ar = wv * 16 + l15;
  #pragma unroll
  for (int ks = 0; ks < 3; ++ks) {
    bf16x8 a = *(const bf16x8*)&A[ar][ks * 32 + kg * 8];
    #pragma unroll
    for (int j = 0; j < 4; ++j) {
      bf16x8 b = *(const bf16x8*)&W[j * 16 + l15][ks * 32 + kg * 8];
      acc[j] = __builtin_amdgcn_mfma_f32_16x16x32_bf16(a, b, acc[j], 0, 0, 0);
    }
  }
}

static __device__ __forceinline__ void gemm_k64(const short (*A)[RPAD], const short (*W)[RPAD],
                                                int wv, int l15, int kg, f32x4* acc) {
  const int ar = wv * 16 + l15;
  #pragma unroll
  for (int ks = 0; ks < 2; ++ks) {
    bf16x8 a = *(const bf16x8*)&A[ar][ks * 32 + kg * 8];
    #pragma unroll
    for (int j = 0; j < 4; ++j) {
      bf16x8 b = *(const bf16x8*)&W[j * 16 + l15][ks * 32 + kg * 8];
      acc[j] = __builtin_amdgcn_mfma_f32_16x16x32_bf16(a, b, acc[j], 0, 0, 0);
    }
  }
}

// A-tile for edges: cols 0..63 = edge_attr row (bf16), 64..66 = x[row_e], 67..95 zero (pre-zeroed).
static __device__ __forceinline__ void stage_edge_A(short (*A)[KPAD], const float* __restrict__ attr,
                                                    const int* __restrict__ ei_row,
                                                    const float* __restrict__ x,
                                                    long e0, int E, int tid) {
  #pragma unroll
  for (int u = 0; u < 4; ++u) {
    int f4 = tid + u * 256;
    int r = f4 >> 4, c4 = (f4 & 15) << 2;
    long e = e0 + r;
    float4 v = make_float4(0.f, 0.f, 0.f, 0.f);
    if (e < E) v = *reinterpret_cast<const float4*>(attr + (size_t)e * HID + c4);
    bf16x4 s; s[0] = f2bf(v.x); s[1] = f2bf(v.y); s[2] = f2bf(v.z); s[3] = f2bf(v.w);
    *reinterpret_cast<bf16x4*>(&A[r][c4]) = s;
  }
  if (tid < 64) {
    long e = e0 + tid;
    float x0 = 0.f, x1 = 0.f, x2 = 0.f;
    if (e < E) {
      int nd = ei_row[e];
      x0 = x[nd * 3]; x1 = x[nd * 3 + 1]; x2 = x[nd * 3 + 2];
    }
    A[tid][64] = f2bf(x0); A[tid][65] = f2bf(x1); A[tid][66] = f2bf(x2);
  }
}

// A-tile for nodes: cols 0..63 = aggsum[n]/max(cnt,1), 64..66 = x[n].
static __device__ __forceinline__ void stage_node_A(short (*A)[KPAD], const float* __restrict__ aggsum,
                                                    const float* __restrict__ cnt,
                                                    const float* __restrict__ x,
                                                    long n0, int N, int tid) {
  #pragma unroll
  for (int u = 0; u < 4; ++u) {
    int f4 = tid + u * 256;
    int r = f4 >> 4, c4 = (f4 & 15) << 2;
    long n = n0 + r;
    float4 v = make_float4(0.f, 0.f, 0.f, 0.f);
    if (n < N) {
      float ic = 1.f / fmaxf(cnt[n], 1.f);
      const float4 t = *reinterpret_cast<const float4*>(aggsum + (size_t)n * HID + c4);
      v.x = t.x * ic; v.y = t.y * ic; v.z = t.z * ic; v.w = t.w * ic;
    }
    bf16x4 s; s[0] = f2bf(v.x); s[1] = f2bf(v.y); s[2] = f2bf(v.z); s[3] = f2bf(v.w);
    *reinterpret_cast<bf16x4*>(&A[r][c4]) = s;
  }
  if (tid < 64) {
    long n = n0 + tid;
    float x0 = 0.f, x1 = 0.f, x2 = 0.f;
    if (n < N) { x0 = x[n * 3]; x1 = x[n * 3 + 1]; x2 = x[n * 3 + 2]; }
    A[tid][64] = f2bf(x0); A[tid][65] = f2bf(x1); A[tid][66] = f2bf(x2);
  }
}

__global__ __launch_bounds__(256) void k_edge_stats(
    const float* __restrict__ attr, const int* __restrict__ ei_row,
    const float* __restrict__ x, const float* __restrict__ w1,
    float* __restrict__ gsum, float* __restrict__ gsq, int E, int numTiles) {
  __shared__ short A[64][KPAD];
  __shared__ short W1s[64][KPAD];
  __shared__ float redS[64], redQ[64];

  const int tid = threadIdx.x;
  const int lane = tid & 63, wv = tid >> 6;
  const int l15 = lane & 15, kg = lane >> 4;

  for (int i = tid; i < 64 * KPAD; i += 256) ((short*)A)[i] = 0;
  stage_w_k96(W1s, w1, tid);
  if (tid < 64) { redS[tid] = 0.f; redQ[tid] = 0.f; }

  float rs[4] = {0.f, 0.f, 0.f, 0.f};
  float rq[4] = {0.f, 0.f, 0.f, 0.f};

  for (int tile = blockIdx.x; tile < numTiles; tile += gridDim.x) {
    __syncthreads();
    stage_edge_A(A, attr, ei_row, x, (long)tile * 64, E, tid);
    __syncthreads();
    f32x4 acc[4];
    const f32x4 z = {0.f, 0.f, 0.f, 0.f};
    acc[0] = z; acc[1] = z; acc[2] = z; acc[3] = z;
    gemm_k96(A, W1s, wv, l15, kg, acc);
    // padded rows (e >= E) are all-zero -> contribute 0 to both sums; denominator is E.
    #pragma unroll
    for (int j = 0; j < 4; ++j) {
      float s = 0.f, q = 0.f;
      #pragma unroll
      for (int rg = 0; rg < 4; ++rg) { float v = acc[j][rg]; s += v; q += v * v; }
      rs[j] += s; rq[j] += q;
    }
  }
  __syncthreads();
  #pragma unroll
  for (int j = 0; j < 4; ++j) {
    atomicAdd(&redS[j * 16 + l15], rs[j]);
    atomicAdd(&redQ[j * 16 + l15], rq[j]);
  }
  __syncthreads();
  if (tid < 64) { atomicAdd(&gsum[tid], redS[tid]); atomicAdd(&gsq[tid], redQ[tid]); }
}

__global__ void k_finalize(const float* __restrict__ gsum, const float* __restrict__ gsq,
                           const float* __restrict__ g, const float* __restrict__ be,
                           float* __restrict__ scale, float* __restrict__ shift, float denom) {
  int t = threadIdx.x;
  if (t < 64) {
    float m = gsum[t] / denom;
    float var = gsq[t] / denom - m * m;
    float is = rsqrtf(var + BN_EPS);
    float sc = g[t] * is;
    scale[t] = sc;
    shift[t] = be[t] - m * sc;
  }
}

__global__ __launch_bounds__(256) void k_edge_main(
    const float* __restrict__ attr, const int* __restrict__ ei_row,
    const int* __restrict__ ei_col, const float* __restrict__ x,
    const float* __restrict__ w1, const float* __restrict__ w2,
    const float* __restrict__ b2, const float* __restrict__ scaleE,
    const float* __restrict__ shiftE,
    float* __restrict__ aggsum, float* __restrict__ cnt, int E, int numTiles) {
  __shared__ short A[64][KPAD];
  __shared__ short W1s[64][KPAD];
  __shared__ short R[64][RPAD];
  __shared__ short W2s[64][RPAD];
  __shared__ float sclS[64], shtS[64], b2S[64];
  __shared__ int colS[64];

  const int tid = threadIdx.x;
  const int lane = tid & 63, wv = tid >> 6;
  const int l15 = lane & 15, kg = lane >> 4;

  for (int i = tid; i < 64 * KPAD; i += 256) ((short*)A)[i] = 0;
  stage_w_k96(W1s, w1, tid);
  stage_w_k64(W2s, w2, tid);
  if (tid < 64) { sclS[tid] = scaleE[tid]; shtS[tid] = shiftE[tid]; b2S[tid] = b2[tid]; }

  const f32x4 z = {0.f, 0.f, 0.f, 0.f};

  for (int tile = blockIdx.x; tile < numTiles; tile += gridDim.x) {
    __syncthreads();   // prev iteration's reads of A/colS/R done
    stage_edge_A(A, attr, ei_row, x, (long)tile * 64, E, tid);
    if (tid < 64) {
      long e = (long)tile * 64 + tid;
      int c = (e < E) ? ei_col[e] : -1;
      colS[tid] = c;
      if (c >= 0) atomicAdd(&cnt[c], 1.f);
    }
    __syncthreads();

    f32x4 acc1[4];
    acc1[0] = z; acc1[1] = z; acc1[2] = z; acc1[3] = z;
    gemm_k96(A, W1s, wv, l15, kg, acc1);

    // BN + ReLU in f32, re-fragment through LDS for GEMM2.
    #pragma unroll
    for (int j = 0; j < 4; ++j) {
      int c = j * 16 + l15;
      float sc = sclS[c], sh = shtS[c];
      #pragma unroll
      for (int rg = 0; rg < 4; ++rg) {
        float v = fmaxf(acc1[j][rg] * sc + sh, 0.f);
        R[wv * 16 + kg * 4 + rg][c] = f2bf(v);
      }
    }
    __syncthreads();

    f32x4 acc2[4];
    acc2[0] = z; acc2[1] = z; acc2[2] = z; acc2[3] = z;
    gemm_k64(R, W2s, wv, l15, kg, acc2);

    // scatter: h2[e][c] += into aggsum[col[e]][c]
    #pragma unroll
    for (int j = 0; j < 4; ++j) {
      int c = j * 16 + l15;
      float bb = b2S[c];
      #pragma unroll
      for (int rg = 0; rg < 4; ++rg) {
        int nd = colS[wv * 16 + kg * 4 + rg];
        if (nd >= 0) atomicAdd(&aggsum[(size_t)nd * HID + c], acc2[j][rg] + bb);
      }
    }
  }
}

__global__ __launch_bounds__(256) void k_node_stats(
    const float* __restrict__ aggsum, const float* __restrict__ cnt,
    const float* __restrict__ x, const float* __restrict__ w3,
    float* __restrict__ gsum, float* __restrict__ gsq, int N, int numTiles) {
  __shared__ short A[64][KPAD];
  __shared__ short W3s[64][KPAD];
  __shared__ float redS[64], redQ[64];

  const int tid = threadIdx.x;
  const int lane = tid & 63, wv = tid >> 6;
  const int l15 = lane & 15, kg = lane >> 4;

  for (int i = tid; i < 64 * KPAD; i += 256) ((short*)A)[i] = 0;
  stage_w_k96(W3s, w3, tid);
  if (tid < 64) { redS[tid] = 0.f; redQ[tid] = 0.f; }

  float rs[4] = {0.f, 0.f, 0.f, 0.f};
  float rq[4] = {0.f, 0.f, 0.f, 0.f};

  for (int tile = blockIdx.x; tile < numTiles; tile += gridDim.x) {
    __syncthreads();
    stage_node_A(A, aggsum, cnt, x, (long)tile * 64, N, tid);
    __syncthreads();
    f32x4 acc[4];
    const f32x4 z = {0.f, 0.f, 0.f, 0.f};
    acc[0] = z; acc[1] = z; acc[2] = z; acc[3] = z;
    gemm_k96(A, W3s, wv, l15, kg, acc);
    #pragma unroll
    for (int j = 0; j < 4; ++j) {
      float s = 0.f, q = 0.f;
      #pragma unroll
      for (int rg = 0; rg < 4; ++rg) { float v = acc[j][rg]; s += v; q += v * v; }
      rs[j] += s; rq[j] += q;
    }
  }
  __syncthreads();
  #pragma unroll
  for (int j = 0; j < 4; ++j) {
    atomicAdd(&redS[j * 16 + l15], rs[j]);
    atomicAdd(&redQ[j * 16 + l15], rq[j]);
  }
  __syncthreads();
  if (tid < 64) { atomicAdd(&gsum[tid], redS[tid]); atomicAdd(&gsq[tid], redQ[tid]); }
}

__global__ __launch_bounds__(256) void k_node_main(
    const float* __restrict__ aggsum, const float* __restrict__ cnt,
    const float* __restrict__ x, const float* __restrict__ w3,
    const float* __restrict__ w4, const float* __restrict__ b4,
    const float* __restrict__ scaleN, const float* __restrict__ shiftN,
    float* __restrict__ out, int N, int numTiles) {
  __shared__ short A[64][KPAD];
  __shared__ short W3s[64][KPAD];
  __shared__ short R[64][RPAD];
  __shared__ short W4s[64][RPAD];
  __shared__ float sclS[64], shtS[64], b4S[64];

  const int tid = threadIdx.x;
  const int lane = tid & 63, wv = tid >> 6;
  const int l15 = lane & 15, kg = lane >> 4;

  for (int i = tid; i < 64 * KPAD; i += 256) ((short*)A)[i] = 0;
  stage_w_k96(W3s, w3, tid);
  stage_w_k64(W4s, w4, tid);
  if (tid < 64) { sclS[tid] = scaleN[tid]; shtS[tid] = shiftN[tid]; b4S[tid] = b4[tid]; }

  const f32x4 z = {0.f, 0.f, 0.f, 0.f};

  for (int tile = blockIdx.x; tile < numTiles; tile += gridDim.x) {
    __syncthreads();
    stage_node_A(A, aggsum, cnt, x, (long)tile * 64, N, tid);
    __syncthreads();

    f32x4 acc1[4];
    acc1[0] = z; acc1[1] = z; acc1[2] = z; acc1[3] = z;
    gemm_k96(A, W3s, wv, l15, kg, acc1);

    #pragma unroll
    for (int j = 0; j < 4; ++j) {
      int c = j * 16 + l15;
      float sc = sclS[c], sh = shtS[c];
      #pragma unroll
      for (int rg = 0; rg < 4; ++rg) {
        float v = fmaxf(acc1[j][rg] * sc + sh, 0.f);
        R[wv * 16 + kg * 4 + rg][c] = f2bf(v);
      }
    }
    __syncthreads();

    f32x4 acc2[4];
    acc2[0] = z; acc2[1] = z; acc2[2] = z; acc2[3] = z;
    gemm_k64(R, W4s, wv, l15, kg, acc2);

    long n0 = (long)tile * 64;
    #pragma unroll
    for (int j = 0; j < 4; ++j) {
      int c = j * 16 + l15;
      float bb = b4S[c];
      #pragma unroll
      for (int rg = 0; rg < 4; ++rg) {
        long n = n0 + wv * 16 + kg * 4 + rg;
        if (n < N) out[(size_t)n * HID + c] = acc2[j][rg] + bb;
      }
    }
  }
}

extern "C" void kernel_launch(void* const* d_in, const int* in_sizes, int n_in,
                              void* d_out, int out_size, void* d_ws, size_t ws_size,
                              hipStream_t stream) {
  const float* x    = (const float*)d_in[0];
  const int*   ei   = (const int*)d_in[1];   // [2, E] int32: row = ei[0:E), col = ei[E:2E)
  const float* attr = (const float*)d_in[2];
  const float* w1   = (const float*)d_in[5];
  const float* g1   = (const float*)d_in[7];
  const float* be1  = (const float*)d_in[8];
  const float* w2   = (const float*)d_in[9];
  const float* b2   = (const float*)d_in[10];
  const float* w3   = (const float*)d_in[11];
  const float* g3   = (const float*)d_in[13];
  const float* be3  = (const float*)d_in[14];
  const float* w4   = (const float*)d_in[15];
  const float* b4   = (const float*)d_in[16];
  float* out = (float*)d_out;

  const int N = in_sizes[0] / 3;
  const int E = in_sizes[1] / 2;

  float* wsf = (float*)d_ws;
  float* gsumE  = wsf + 0;
  float* gsqE   = wsf + 64;
  float* scaleE = wsf + 128;
  float* shiftE = wsf + 192;
  float* gsumN  = wsf + 256;
  float* gsqN   = wsf + 320;
  float* scaleN = wsf + 384;
  float* shiftN = wsf + 448;
  float* aggsum = wsf + 512;
  float* cnt    = wsf + 512 + (size_t)N * HID;

  hipMemsetAsync(d_ws, 0, (512 + (size_t)N * HID + (size_t)N) * sizeof(float), stream);

  const int tilesE = (E + 63) / 64;
  const int tilesN = (N + 63) / 64;
  const int gridE = tilesE < 2048 ? tilesE : 2048;

  k_edge_stats<<<gridE, 256, 0, stream>>>(attr, ei, x, w1, gsumE, gsqE, E, tilesE);
  k_finalize<<<1, 64, 0, stream>>>(gsumE, gsqE, g1, be1, scaleE, shiftE, (float)E);
  k_edge_main<<<gridE, 256, 0, stream>>>(attr, ei, ei + E, x, w1, w2, b2, scaleE, shiftE,
                                         aggsum, cnt, E, tilesE);
  k_node_stats<<<tilesN, 256, 0, stream>>>(aggsum, cnt, x, w3, gsumN, gsqN, N, tilesN);
  k_finalize<<<1, 64, 0, stream>>>(gsumN, gsqN, g3, be3, scaleN, shiftN, (float)N);
  k_node_main<<<tilesN, 256, 0, stream>>>(aggsum, cnt, x, w3, w4, b4, scaleN, shiftN, out, N, tilesN);
}